// Round 6
// baseline (161.406 us; speedup 1.0000x reference)
//
#include <hip/hip_runtime.h>
#include <hip/hip_cooperative_groups.h>
#include <math.h>

namespace cg = cooperative_groups;

#define EPSV 1e-6f
constexpr int N_ = 900, B_ = 8, C_ = 256, H_ = 8, D_ = 32;
constexpr int M_TOT = N_ * B_;        // 7200 rows
constexpr int BM1 = 16;               // rows per block
constexpr int NBLK1 = M_TOT / BM1;    // 450 blocks
constexpr int QS = 264;               // fp32 LDS row stride (floats)
constexpr int LDS1 = 8192*2 + 3 * BM1 * QS * 4;   // 67072 bytes

typedef __attribute__((ext_vector_type(8))) short short8;       // 8 bf16
typedef __attribute__((ext_vector_type(4))) float f32x4;
typedef __attribute__((ext_vector_type(2))) float f32x2;
typedef __attribute__((ext_vector_type(2))) unsigned short us2;

__device__ __forceinline__ unsigned short f2bf(float f) {   // RNE fp32->bf16
    unsigned int u = __float_as_uint(f);
    return (unsigned short)((u + 0x7FFFu + ((u >> 16) & 1u)) >> 16);
}
// swizzled byte offset in a [rows]x256-bf16 LDS tile (row stride 512B)
__device__ __forceinline__ int swz(int row, int kElem) {
    int b = (row << 9) + (kElem << 1);
    return b ^ ((row & 7) << 4);
}
__device__ __forceinline__ float red16(float v) {  // sum over 16-lane group
    v += __shfl_xor(v, 1); v += __shfl_xor(v, 2);
    v += __shfl_xor(v, 4); v += __shfl_xor(v, 8);
    return v;
}

// ---------------------------------------------------------------------------
// Phase bodies (shared between the cooperative kernel and the fallback path)
// ---------------------------------------------------------------------------
__device__ __forceinline__ void packw_body(int gt,
    const float* __restrict__ Wq, const float* __restrict__ Wk,
    const float* __restrict__ Wv, const float* __restrict__ Wo,
    unsigned short* __restrict__ wbf)
{
    if (gt < 32768) {
        const int i = gt * 8;
        const float* src = (i < 65536) ? Wq : (i < 131072) ? Wk
                         : (i < 196608) ? Wv : Wo;
        const int off = i & 65535;
        const float4 a = *reinterpret_cast<const float4*>(src + off);
        const float4 b = *reinterpret_cast<const float4*>(src + off + 4);
        short8 p;
        p[0]=(short)f2bf(a.x); p[1]=(short)f2bf(a.y);
        p[2]=(short)f2bf(a.z); p[3]=(short)f2bf(a.w);
        p[4]=(short)f2bf(b.x); p[5]=(short)f2bf(b.y);
        p[6]=(short)f2bf(b.z); p[7]=(short)f2bf(b.w);
        *reinterpret_cast<short8*>(wbf + i) = p;
    }
}

// 16-row x 256-col GEMM: A from swizzled LDS (bf16), W bf16 from global (L2).
__device__ __forceinline__ void gemm16(const unsigned char* As,
                                       const unsigned short* Wg,
                                       int cw, int lrow, int kg8,
                                       f32x4 acc[4])
{
    #pragma unroll
    for (int kk = 0; kk < C_; kk += 32) {
        const short8 af = *reinterpret_cast<const short8*>(As + swz(lrow, kk + kg8));
        #pragma unroll
        for (int j = 0; j < 4; ++j) {
            const short8 bf = *reinterpret_cast<const short8*>(
                Wg + (size_t)(cw + j*16 + lrow) * C_ + kk + kg8);
            acc[j] = __builtin_amdgcn_mfma_f32_16x16x32_bf16(af, bf, acc[j], 0, 0, 0);
        }
    }
}

__device__ __forceinline__ void qkva_body(char* smem, int bid,
    const float* __restrict__ query, const float* __restrict__ key,
    const float* __restrict__ qpos,  const float* __restrict__ kpos,
    const unsigned short* __restrict__ wbf,
    const float* __restrict__ bq, const float* __restrict__ bk,
    const float* __restrict__ bv,
    unsigned short* __restrict__ abf)
{
    unsigned char* Aq = (unsigned char*)smem;            // 8 KB
    unsigned char* Ak = (unsigned char*)smem + 8192;     // 8 KB
    float* q_s = (float*)(smem + 16384);                 // [16][264]
    float* k_s = q_s + BM1 * QS;
    float* v_s = k_s + BM1 * QS;

    const int tid = threadIdx.x;
    const int r0  = bid * BM1;

    // stage query/key rows -> bf16 swizzled LDS
    {
        const int trow = tid >> 5, k0 = (tid & 31) * 8;
        #pragma unroll
        for (int i = 0; i < 2; ++i) {
            const int row = trow + i * 8;
            const float* xr = query + (size_t)(r0 + row) * C_ + k0;
            const float4 a0 = *reinterpret_cast<const float4*>(xr);
            const float4 a1 = *reinterpret_cast<const float4*>(xr + 4);
            short8 pa;
            pa[0]=(short)f2bf(a0.x); pa[1]=(short)f2bf(a0.y);
            pa[2]=(short)f2bf(a0.z); pa[3]=(short)f2bf(a0.w);
            pa[4]=(short)f2bf(a1.x); pa[5]=(short)f2bf(a1.y);
            pa[6]=(short)f2bf(a1.z); pa[7]=(short)f2bf(a1.w);
            *reinterpret_cast<short8*>(Aq + swz(row, k0)) = pa;
            const float* kr = key + (size_t)(r0 + row) * C_ + k0;
            const float4 b0 = *reinterpret_cast<const float4*>(kr);
            const float4 b1 = *reinterpret_cast<const float4*>(kr + 4);
            short8 pb;
            pb[0]=(short)f2bf(b0.x); pb[1]=(short)f2bf(b0.y);
            pb[2]=(short)f2bf(b0.z); pb[3]=(short)f2bf(b0.w);
            pb[4]=(short)f2bf(b1.x); pb[5]=(short)f2bf(b1.y);
            pb[6]=(short)f2bf(b1.z); pb[7]=(short)f2bf(b1.w);
            *reinterpret_cast<short8*>(Ak + swz(row, k0)) = pb;
        }
    }
    __syncthreads();

    const int wave = tid >> 6, lane = tid & 63;
    const int cw = wave * 64;
    const int lrow = lane & 15, kg8 = (lane >> 4) * 8;
    const int crow0 = (lane >> 4) * 4, ccol = lane & 15;

    // q/k/v GEMMs -> LDS fp32 (sigmoid on q,k)
    {
        f32x4 acc[4] = {};
        gemm16(Aq, wbf + 0*65536, cw, lrow, kg8, acc);
        #pragma unroll
        for (int j = 0; j < 4; ++j) {
            const int ch = cw + j*16 + ccol;
            const float bias_v = bq[ch];
            #pragma unroll
            for (int r = 0; r < 4; ++r) {
                const int row = crow0 + r;
                float v = acc[j][r] + bias_v + qpos[(size_t)(r0+row)*C_ + ch];
                q_s[row*QS + ch] = 1.f / (1.f + expf(-v));
            }
        }
    }
    {
        f32x4 acc[4] = {};
        gemm16(Ak, wbf + 1*65536, cw, lrow, kg8, acc);
        #pragma unroll
        for (int j = 0; j < 4; ++j) {
            const int ch = cw + j*16 + ccol;
            const float bias_v = bk[ch];
            #pragma unroll
            for (int r = 0; r < 4; ++r) {
                const int row = crow0 + r;
                float v = acc[j][r] + bias_v + kpos[(size_t)(r0+row)*C_ + ch];
                k_s[row*QS + ch] = 1.f / (1.f + expf(-v));
            }
        }
    }
    {
        f32x4 acc[4] = {};
        gemm16(Ak, wbf + 2*65536, cw, lrow, kg8, acc);
        #pragma unroll
        for (int j = 0; j < 4; ++j) {
            const int ch = cw + j*16 + ccol;
            const float bias_v = bv[ch];
            #pragma unroll
            for (int r = 0; r < 4; ++r) {
                const int row = crow0 + r;
                v_s[row*QS + ch] = acc[j][r] + bias_v;
            }
        }
    }
    __syncthreads();

    // per-location attention, 16 threads/location
    {
        const int loc = tid >> 4, tt = tid & 15, d0 = tt * 2;
        const int gr = r0 + loc;                 // global row in (n,b) order
        const int nn = gr >> 3, bb = gr & 7;
        const float* qr = q_s + loc * QS + d0;
        const float* kr = k_s + loc * QS + d0;
        const float* vr = v_s + loc * QS + d0;
        f32x2 qh[8], kh[8], vh[8];
        #pragma unroll
        for (int h = 0; h < 8; ++h) {
            qh[h] = *reinterpret_cast<const f32x2*>(qr + h*32);
            kh[h] = *reinterpret_cast<const f32x2*>(kr + h*32);
            vh[h] = *reinterpret_cast<const f32x2*>(vr + h*32);
        }

        float ir1[8], so_[8];
        {
            f32x2 ck = {0,0}, cq = {0,0};
            #pragma unroll
            for (int h = 0; h < 8; ++h) {
                float p1 = 0.f, p2 = 0.f;
                #pragma unroll
                for (int j = 0; j < 2; ++j) {
                    ck[j] += kh[h][j]; cq[j] += qh[h][j];
                    p1 += (qh[h][j] + EPSV) * (ck[j] + EPSV);
                    p2 += (kh[h][j] + EPSV) * (cq[j] + EPSV);
                }
                p1 = red16(p1); p2 = red16(p2);
                ir1[h] = 1.f / p1;
                so_[h] = (float)(h+1) / p2;
            }
        }
        float salloc[8], scomp[8];
        {
            f32x2 c2 = {0,0}, c3 = {0,0};
            float css = 0.f;
            #pragma unroll
            for (int h = 0; h < 8; ++h) {
                const float sih = (float)(h+1) * ir1[h];
                float p3 = 0.f, p4 = 0.f;
                #pragma unroll
                for (int j = 0; j < 2; ++j) {
                    c2[j] += kh[h][j] * so_[h];
                    c3[j] += qh[h][j] * sih;
                    p3 += (qh[h][j] + EPSV) * (c2[j] + EPSV);
                    p4 += (kh[h][j] + EPSV) * (c3[j] + EPSV);
                }
                p3 = red16(p3); p4 = red16(p4);
                const float inv_n = 1.f / (float)(h+1);
                salloc[h] = 1.f / (1.f + expf(-p3 * inv_n));
                const float consrc = fminf(1.f, fmaxf(-1.f, p4 * inv_n));
                const float cs = expf(consrc);
                css += cs;
                scomp[h] = cs / css * (float)(h+1);
            }
        }
        #pragma unroll
        for (int h = 0; h < 8; ++h) {
            f32x2 qs2, a2 = {0,0};
            #pragma unroll
            for (int j = 0; j < 2; ++j) qs2[j] = qh[h][j] * ir1[h];
            #pragma unroll
            for (int h2 = 0; h2 <= h; ++h2) {
                float p = 0.f;
                #pragma unroll
                for (int j = 0; j < 2; ++j) p += qs2[j] * kh[h2][j];
                p = red16(p);
                const float w = p * scomp[h2];
                #pragma unroll
                for (int j = 0; j < 2; ++j) a2[j] += w * vh[h2][j];
            }
            us2 o;
            o[0] = f2bf(a2[0] * salloc[h]);
            o[1] = f2bf(a2[1] * salloc[h]);
            *reinterpret_cast<us2*>(abf + (size_t)bb*(H_*N_*D_) + (size_t)h*(N_*D_)
                                        + (size_t)nn*D_ + d0) = o;
        }
    }
}

__device__ __forceinline__ void outproj_body(char* smem, int bid,
    const unsigned short* __restrict__ abf,
    const unsigned short* __restrict__ wbf,
    const float* __restrict__ bo,
    const float* __restrict__ query,
    float* __restrict__ out)
{
    unsigned char* As = (unsigned char*)smem;   // 8 KB, reuses Aq region
    const int tid = threadIdx.x;
    const int r0  = bid * BM1;

    {   // stage scrambled A rows: out row gr=(n,b) <- abf[b*N*C + n*256 ...]
        const int trow = tid >> 5, k0 = (tid & 31) * 8;
        #pragma unroll
        for (int i = 0; i < 2; ++i) {
            const int row = trow + i * 8;
            const int gr = r0 + row;
            const int nn = gr >> 3, bb = gr & 7;
            const short8 p = *reinterpret_cast<const short8*>(
                abf + (size_t)bb * (N_*C_) + (size_t)nn * C_ + k0);
            *reinterpret_cast<short8*>(As + swz(row, k0)) = p;
        }
    }
    __syncthreads();

    const int wave = tid >> 6, lane = tid & 63;
    const int cw = wave * 64;
    const int lrow = lane & 15, kg8 = (lane >> 4) * 8;
    const int crow0 = (lane >> 4) * 4, ccol = lane & 15;

    f32x4 acc[4] = {};
    gemm16(As, wbf + 3*65536, cw, lrow, kg8, acc);

    #pragma unroll
    for (int j = 0; j < 4; ++j) {
        const int ch = cw + j*16 + ccol;
        const float bias_v = bo[ch];
        #pragma unroll
        for (int r = 0; r < 4; ++r) {
            const int row = crow0 + r;
            const size_t g = (size_t)(r0 + row) * C_ + ch;
            out[g] = acc[j][r] + bias_v + query[g];
        }
    }
}

// ---------------------------------------------------------------------------
// Cooperative all-in-one kernel
// ---------------------------------------------------------------------------
__global__ __launch_bounds__(256, 2)
void lca_coop(const float* __restrict__ query, const float* __restrict__ key,
              const float* __restrict__ qpos,  const float* __restrict__ kpos,
              const float* __restrict__ Wq, const float* __restrict__ Wk,
              const float* __restrict__ Wv, const float* __restrict__ Wo,
              const float* __restrict__ bq, const float* __restrict__ bk,
              const float* __restrict__ bv, const float* __restrict__ bo,
              unsigned short* __restrict__ wbf, unsigned short* __restrict__ abf,
              float* __restrict__ out)
{
    extern __shared__ char smem[];
    cg::grid_group grid = cg::this_grid();

    packw_body(blockIdx.x * 256 + threadIdx.x, Wq, Wk, Wv, Wo, wbf);
    grid.sync();
    qkva_body(smem, blockIdx.x, query, key, qpos, kpos, wbf, bq, bk, bv, abf);
    grid.sync();
    outproj_body(smem, blockIdx.x, abf, wbf, bo, query, out);
}

// ---------------------------------------------------------------------------
// Fallback kernels (round-5 path) in case cooperative launch is rejected
// ---------------------------------------------------------------------------
__global__ __launch_bounds__(256)
void pack_w_k(const float* __restrict__ Wq, const float* __restrict__ Wk,
              const float* __restrict__ Wv, const float* __restrict__ Wo,
              unsigned short* __restrict__ wbf)
{
    packw_body(blockIdx.x * 256 + threadIdx.x, Wq, Wk, Wv, Wo, wbf);
}

__global__ __launch_bounds__(256, 2)
void fused_qkva_k(const float* __restrict__ query, const float* __restrict__ key,
                  const float* __restrict__ qpos,  const float* __restrict__ kpos,
                  const unsigned short* __restrict__ wbf,
                  const float* __restrict__ bq, const float* __restrict__ bk,
                  const float* __restrict__ bv,
                  unsigned short* __restrict__ abf)
{
    extern __shared__ char smem[];
    qkva_body(smem, blockIdx.x, query, key, qpos, kpos, wbf, bq, bk, bv, abf);
}

__global__ __launch_bounds__(256, 2)
void outproj_k(const unsigned short* __restrict__ abf,
               const unsigned short* __restrict__ wbf,
               const float* __restrict__ bo,
               const float* __restrict__ query,
               float* __restrict__ out)
{
    extern __shared__ char smem[];
    outproj_body(smem, blockIdx.x, abf, wbf, bo, query, out);
}

// ---------------------------------------------------------------------------
extern "C" void kernel_launch(void* const* d_in, const int* in_sizes, int n_in,
                              void* d_out, int out_size, void* d_ws, size_t ws_size,
                              hipStream_t stream)
{
    const float* query = (const float*)d_in[0];
    const float* key   = (const float*)d_in[1];
    const float* qpos  = (const float*)d_in[2];
    const float* kpos  = (const float*)d_in[3];
    const float* Wq = (const float*)d_in[4];  const float* bq = (const float*)d_in[5];
    const float* Wk = (const float*)d_in[6];  const float* bk = (const float*)d_in[7];
    const float* Wv = (const float*)d_in[8];  const float* bv = (const float*)d_in[9];
    const float* Wo = (const float*)d_in[10]; const float* bo = (const float*)d_in[11];

    unsigned short* wbf = (unsigned short*)d_ws;        // 4*65536 bf16 = 512 KB
    unsigned short* abf = wbf + 4*65536;                // B*N*C bf16 = 3.7 MB
    float* out = (float*)d_out;

    void* args[] = {
        (void*)&query, (void*)&key, (void*)&qpos, (void*)&kpos,
        (void*)&Wq, (void*)&Wk, (void*)&Wv, (void*)&Wo,
        (void*)&bq, (void*)&bk, (void*)&bv, (void*)&bo,
        (void*)&wbf, (void*)&abf, (void*)&out };

    hipError_t err = hipLaunchCooperativeKernel(
        (const void*)lca_coop, dim3(NBLK1), dim3(256), args,
        (unsigned int)LDS1, stream);

    if (err != hipSuccess) {
        (void)hipGetLastError();   // clear sticky error, take fallback path
        pack_w_k<<<128, 256, 0, stream>>>(Wq, Wk, Wv, Wo, wbf);
        fused_qkva_k<<<NBLK1, 256, LDS1, stream>>>(query, key, qpos, kpos, wbf,
                                                   bq, bk, bv, abf);
        outproj_k<<<NBLK1, 256, 8192, stream>>>(abf, wbf, bo, query, out);
    }
}

// Round 7
// 77.894 us; speedup vs baseline: 2.0721x; 2.0721x over previous
//
#include <hip/hip_runtime.h>
#include <math.h>

#define EPSV 1e-6f
constexpr int N_ = 900, B_ = 8, C_ = 256, H_ = 8, D_ = 32;
constexpr int L_ = 12;               // new rows per chunk
constexpr int S_ = 16;               // staged rows per chunk (4 overlap)
constexpr int NCH = N_ / L_;         // 75 chunks per batch
constexpr int QS  = 264;             // fp32 LDS row stride (floats)
constexpr int AOS = 264;             // attnO row stride (shorts)
// LDS layout: Aq 8K | Ak 8K | q_s 16.5K | k_s | v_s | attnO 8.25K
constexpr int OFF_AK = 8192;
constexpr int OFF_Q  = 16384;
constexpr int OFF_K  = OFF_Q + S_ * QS * 4;
constexpr int OFF_V  = OFF_K + S_ * QS * 4;
constexpr int OFF_AO = OFF_V + S_ * QS * 4;
constexpr int LDS1   = OFF_AO + S_ * AOS * 2;   // 75520 bytes

typedef __attribute__((ext_vector_type(8))) short short8;       // 8 bf16
typedef __attribute__((ext_vector_type(4))) float f32x4;
typedef __attribute__((ext_vector_type(2))) float f32x2;
typedef __attribute__((ext_vector_type(2))) unsigned short us2;

__device__ __forceinline__ unsigned short f2bf(float f) {   // RNE fp32->bf16
    unsigned int u = __float_as_uint(f);
    return (unsigned short)((u + 0x7FFFu + ((u >> 16) & 1u)) >> 16);
}
// swizzled byte offset in a [rows]x256-bf16 LDS tile (row stride 512B)
__device__ __forceinline__ int swz(int row, int kElem) {
    int b = (row << 9) + (kElem << 1);
    return b ^ ((row & 7) << 4);
}
__device__ __forceinline__ float red16(float v) {  // sum over 16-lane group
    v += __shfl_xor(v, 1); v += __shfl_xor(v, 2);
    v += __shfl_xor(v, 4); v += __shfl_xor(v, 8);
    return v;
}

// ---------------------------------------------------------------------------
// prep: pack Wq|Wk|Wv|Wo (fp32 row-major 256x256) -> bf16, concatenated.
// ---------------------------------------------------------------------------
__global__ __launch_bounds__(256)
void pack_w(const float* __restrict__ Wq, const float* __restrict__ Wk,
            const float* __restrict__ Wv, const float* __restrict__ Wo,
            unsigned short* __restrict__ wbf)
{
    const int i = (blockIdx.x * 256 + threadIdx.x) * 8;
    const float* src = (i < 65536) ? Wq : (i < 131072) ? Wk
                     : (i < 196608) ? Wv : Wo;
    const int off = i & 65535;
    const float4 a = *reinterpret_cast<const float4*>(src + off);
    const float4 b = *reinterpret_cast<const float4*>(src + off + 4);
    short8 p;
    p[0]=(short)f2bf(a.x); p[1]=(short)f2bf(a.y);
    p[2]=(short)f2bf(a.z); p[3]=(short)f2bf(a.w);
    p[4]=(short)f2bf(b.x); p[5]=(short)f2bf(b.y);
    p[6]=(short)f2bf(b.z); p[7]=(short)f2bf(b.w);
    *reinterpret_cast<short8*>(wbf + i) = p;
}

// 16-row x 256-col GEMM: A from swizzled LDS (bf16), W bf16 from global (L2).
// Wave owns 64 cols, 1x4 frags, K=256 unrolled -> 32 MFMA.
__device__ __forceinline__ void gemm16(const unsigned char* As,
                                       const unsigned short* Wg,
                                       int cw, int lrow, int kg8,
                                       f32x4 acc[4])
{
    #pragma unroll
    for (int kk = 0; kk < C_; kk += 32) {
        const short8 af = *reinterpret_cast<const short8*>(As + swz(lrow, kk + kg8));
        #pragma unroll
        for (int j = 0; j < 4; ++j) {
            const short8 bf = *reinterpret_cast<const short8*>(
                Wg + (size_t)(cw + j*16 + lrow) * C_ + kk + kg8);
            acc[j] = __builtin_amdgcn_mfma_f32_16x16x32_bf16(af, bf, acc[j], 0, 0, 0);
        }
    }
}

// ---------------------------------------------------------------------------
// One block = (chunk i, batch b): stages n'' in [12i, 12i+16) mod 900,
// does qkv proj + attention for those 16 locations, then the out-projection
// for the 12 out rows n = (113*(t/4)) % 225 + 225k, t = 12i + 4j (j<3,k<4),
// whose scrambled input slices live entirely in this block's attn output.
// ---------------------------------------------------------------------------
__global__ __launch_bounds__(256, 2)
void lca_fused(const float* __restrict__ query, const float* __restrict__ key,
               const float* __restrict__ qpos,  const float* __restrict__ kpos,
               const unsigned short* __restrict__ wbf,
               const float* __restrict__ bq, const float* __restrict__ bk,
               const float* __restrict__ bv, const float* __restrict__ bo,
               float* __restrict__ out)
{
    extern __shared__ char smem[];
    unsigned char* Aq = (unsigned char*)smem;           // 8 KB (reused as outA)
    unsigned char* Ak = (unsigned char*)smem + OFF_AK;  // 8 KB
    float* q_s = (float*)(smem + OFF_Q);                // [16][264] fp32
    float* k_s = (float*)(smem + OFF_K);
    float* v_s = (float*)(smem + OFF_V);
    unsigned short* aO = (unsigned short*)(smem + OFF_AO);  // [16][264] bf16

    const int tid = threadIdx.x;
    const int ic  = blockIdx.x;          // chunk 0..74
    const int b   = blockIdx.y;          // batch 0..7
    const int s   = ic * L_;             // first staged n''

    // ---- phase 0: stage query/key rows (n'' = (s+row) mod 900) -> bf16 LDS
    {
        const int trow = tid >> 5, k0 = (tid & 31) * 8;
        #pragma unroll
        for (int ii = 0; ii < 2; ++ii) {
            const int row = trow + ii * 8;
            int n2 = s + row; if (n2 >= N_) n2 -= N_;
            const size_t base = (size_t)(n2 * B_ + b) * C_ + k0;
            const float4 a0 = *reinterpret_cast<const float4*>(query + base);
            const float4 a1 = *reinterpret_cast<const float4*>(query + base + 4);
            short8 pa;
            pa[0]=(short)f2bf(a0.x); pa[1]=(short)f2bf(a0.y);
            pa[2]=(short)f2bf(a0.z); pa[3]=(short)f2bf(a0.w);
            pa[4]=(short)f2bf(a1.x); pa[5]=(short)f2bf(a1.y);
            pa[6]=(short)f2bf(a1.z); pa[7]=(short)f2bf(a1.w);
            *reinterpret_cast<short8*>(Aq + swz(row, k0)) = pa;
            const float4 b0 = *reinterpret_cast<const float4*>(key + base);
            const float4 b1 = *reinterpret_cast<const float4*>(key + base + 4);
            short8 pb;
            pb[0]=(short)f2bf(b0.x); pb[1]=(short)f2bf(b0.y);
            pb[2]=(short)f2bf(b0.z); pb[3]=(short)f2bf(b0.w);
            pb[4]=(short)f2bf(b1.x); pb[5]=(short)f2bf(b1.y);
            pb[6]=(short)f2bf(b1.z); pb[7]=(short)f2bf(b1.w);
            *reinterpret_cast<short8*>(Ak + swz(row, k0)) = pb;
        }
    }
    __syncthreads();

    const int wave = tid >> 6, lane = tid & 63;
    const int cw = wave * 64;
    const int lrow = lane & 15, kg8 = (lane >> 4) * 8;
    const int crow0 = (lane >> 4) * 4, ccol = lane & 15;

    // per-epilogue global rows for the 4 C-rows this lane owns
    int grs[4];
    #pragma unroll
    for (int r_ = 0; r_ < 4; ++r_) {
        int n2 = s + crow0 + r_; if (n2 >= N_) n2 -= N_;
        grs[r_] = n2 * B_ + b;
    }

    // ---- phase 1: q/k/v GEMMs -> LDS fp32 (sigmoid on q,k) ----
    {
        f32x4 acc[4] = {};
        gemm16(Aq, wbf + 0*65536, cw, lrow, kg8, acc);
        #pragma unroll
        for (int j = 0; j < 4; ++j) {
            const int ch = cw + j*16 + ccol;
            const float bias_v = bq[ch];
            #pragma unroll
            for (int r_ = 0; r_ < 4; ++r_) {
                float v = acc[j][r_] + bias_v + qpos[(size_t)grs[r_] * C_ + ch];
                q_s[(crow0 + r_)*QS + ch] = 1.f / (1.f + expf(-v));
            }
        }
    }
    {
        f32x4 acc[4] = {};
        gemm16(Ak, wbf + 1*65536, cw, lrow, kg8, acc);
        #pragma unroll
        for (int j = 0; j < 4; ++j) {
            const int ch = cw + j*16 + ccol;
            const float bias_v = bk[ch];
            #pragma unroll
            for (int r_ = 0; r_ < 4; ++r_) {
                float v = acc[j][r_] + bias_v + kpos[(size_t)grs[r_] * C_ + ch];
                k_s[(crow0 + r_)*QS + ch] = 1.f / (1.f + expf(-v));
            }
        }
    }
    {
        f32x4 acc[4] = {};
        gemm16(Ak, wbf + 2*65536, cw, lrow, kg8, acc);
        #pragma unroll
        for (int j = 0; j < 4; ++j) {
            const int ch = cw + j*16 + ccol;
            const float bias_v = bv[ch];
            #pragma unroll
            for (int r_ = 0; r_ < 4; ++r_) {
                v_s[(crow0 + r_)*QS + ch] = acc[j][r_] + bias_v;
            }
        }
    }
    __syncthreads();

    // ---- phase 2: per-location attention, 16 threads/location, 16 locs ----
    {
        const int loc = tid >> 4, tt = tid & 15, d0 = tt * 2;
        const float* qr = q_s + loc * QS + d0;
        const float* kr = k_s + loc * QS + d0;
        const float* vr = v_s + loc * QS + d0;
        f32x2 qh[8], kh[8], vh[8];
        #pragma unroll
        for (int h = 0; h < 8; ++h) {
            qh[h] = *reinterpret_cast<const f32x2*>(qr + h*32);
            kh[h] = *reinterpret_cast<const f32x2*>(kr + h*32);
            vh[h] = *reinterpret_cast<const f32x2*>(vr + h*32);
        }

        float ir1[8], so_[8];
        {
            f32x2 ck = {0,0}, cq = {0,0};
            #pragma unroll
            for (int h = 0; h < 8; ++h) {
                float p1 = 0.f, p2 = 0.f;
                #pragma unroll
                for (int j = 0; j < 2; ++j) {
                    ck[j] += kh[h][j]; cq[j] += qh[h][j];
                    p1 += (qh[h][j] + EPSV) * (ck[j] + EPSV);
                    p2 += (kh[h][j] + EPSV) * (cq[j] + EPSV);
                }
                p1 = red16(p1); p2 = red16(p2);
                ir1[h] = 1.f / p1;
                so_[h] = (float)(h+1) / p2;
            }
        }
        float salloc[8], scomp[8];
        {
            f32x2 c2 = {0,0}, c3 = {0,0};
            float css = 0.f;
            #pragma unroll
            for (int h = 0; h < 8; ++h) {
                const float sih = (float)(h+1) * ir1[h];
                float p3 = 0.f, p4 = 0.f;
                #pragma unroll
                for (int j = 0; j < 2; ++j) {
                    c2[j] += kh[h][j] * so_[h];
                    c3[j] += qh[h][j] * sih;
                    p3 += (qh[h][j] + EPSV) * (c2[j] + EPSV);
                    p4 += (kh[h][j] + EPSV) * (c3[j] + EPSV);
                }
                p3 = red16(p3); p4 = red16(p4);
                const float inv_n = 1.f / (float)(h+1);
                salloc[h] = 1.f / (1.f + expf(-p3 * inv_n));
                const float consrc = fminf(1.f, fmaxf(-1.f, p4 * inv_n));
                const float cs = expf(consrc);
                css += cs;
                scomp[h] = cs / css * (float)(h+1);
            }
        }
        #pragma unroll
        for (int h = 0; h < 8; ++h) {
            f32x2 qs2, a2 = {0,0};
            #pragma unroll
            for (int j = 0; j < 2; ++j) qs2[j] = qh[h][j] * ir1[h];
            #pragma unroll
            for (int h2 = 0; h2 <= h; ++h2) {
                float p = 0.f;
                #pragma unroll
                for (int j = 0; j < 2; ++j) p += qs2[j] * kh[h2][j];
                p = red16(p);
                const float w = p * scomp[h2];
                #pragma unroll
                for (int j = 0; j < 2; ++j) a2[j] += w * vh[h2][j];
            }
            us2 o;
            o[0] = f2bf(a2[0] * salloc[h]);
            o[1] = f2bf(a2[1] * salloc[h]);
            *reinterpret_cast<us2*>(aO + loc*AOS + (h << 5) + d0) = o;
        }
    }
    __syncthreads();

    // ---- phase 3: gather scrambled out-proj A rows into swizzled tile ----
    // out A row (j,k): c-th elem = aO[4j + (c>>5)][h*32 + (c&31)],
    // h = (8n + (c>>5)) / 900, n = (113*(t/4)) % 225 + 225k, t = 12i+4j.
    {
        const int row_a = tid >> 4, seg = tid & 15;
        if (row_a < L_) {
            const int jA = row_a >> 2, kA = row_a & 3;
            const int tv = s + 4 * jA;
            const int n  = (113 * (tv >> 2)) % 225 + 225 * kA;
            #pragma unroll
            for (int cp = 0; cp < 8; ++cp) {
                const int c  = seg * 16 + cp * 2;
                const int jj = c >> 5;
                const int h  = (8 * n + jj) / 900;
                const int r  = 4 * jA + jj;
                const us2 v = *reinterpret_cast<const us2*>(
                    aO + r*AOS + (h << 5) + (c & 31));
                *reinterpret_cast<us2*>(Aq + swz(row_a, c)) = v;
            }
        } else {
            const us2 z = {0, 0};
            #pragma unroll
            for (int cp = 0; cp < 8; ++cp) {
                const int c = seg * 16 + cp * 2;
                *reinterpret_cast<us2*>(Aq + swz(row_a, c)) = z;
            }
        }
    }
    __syncthreads();

    // ---- phase 4: out-projection + residual -> d_out ----
    {
        f32x4 acc[4] = {};
        gemm16(Aq, wbf + 3*65536, cw, lrow, kg8, acc);
        #pragma unroll
        for (int j = 0; j < 4; ++j) {
            const int ch = cw + j*16 + ccol;
            const float bias_v = bo[ch];
            #pragma unroll
            for (int r_ = 0; r_ < 4; ++r_) {
                const int row_a = crow0 + r_;
                if (row_a < L_) {
                    const int jA = row_a >> 2, kA = row_a & 3;
                    const int tv = s + 4 * jA;
                    const int n  = (113 * (tv >> 2)) % 225 + 225 * kA;
                    const size_t g = (size_t)(n * B_ + b) * C_ + ch;
                    out[g] = acc[j][r_] + bias_v + query[g];
                }
            }
        }
    }
}

// ---------------------------------------------------------------------------
extern "C" void kernel_launch(void* const* d_in, const int* in_sizes, int n_in,
                              void* d_out, int out_size, void* d_ws, size_t ws_size,
                              hipStream_t stream)
{
    const float* query = (const float*)d_in[0];
    const float* key   = (const float*)d_in[1];
    const float* qpos  = (const float*)d_in[2];
    const float* kpos  = (const float*)d_in[3];
    const float* Wq = (const float*)d_in[4];  const float* bq = (const float*)d_in[5];
    const float* Wk = (const float*)d_in[6];  const float* bk = (const float*)d_in[7];
    const float* Wv = (const float*)d_in[8];  const float* bv = (const float*)d_in[9];
    const float* Wo = (const float*)d_in[10]; const float* bo = (const float*)d_in[11];

    unsigned short* wbf = (unsigned short*)d_ws;   // 4 x 65536 bf16 = 512 KB
    float* out = (float*)d_out;

    pack_w<<<128, 256, 0, stream>>>(Wq, Wk, Wv, Wo, wbf);
    lca_fused<<<dim3(NCH, B_), 256, LDS1, stream>>>(
        query, key, qpos, kpos, wbf, bq, bk, bv, bo, out);
}

// Round 8
// 59.155 us; speedup vs baseline: 2.7285x; 1.3168x over previous
//
#include <hip/hip_runtime.h>
#include <math.h>

#define EPSV 1e-6f
constexpr int N_ = 900, B_ = 8, C_ = 256, H_ = 8, D_ = 32;
constexpr int M_TOT = N_ * B_;        // 7200 rows
constexpr int BM1 = 16;               // rows per block, kernel 1
constexpr int NBLK1 = M_TOT / BM1;    // 450 blocks
constexpr int BM2 = 32;               // rows per block, kernel 2
constexpr int NBLK2 = M_TOT / BM2;    // 225 row-blocks (x4 col-quarters)
constexpr int VS  = 272;              // q/k/v LDS row stride (shorts)
// kernel-1 LDS: [0,16384) staging Aq|Ak, later overlaid by v_sb (8704 B)
constexpr int OFF_QS = 16384;
constexpr int OFF_KS = OFF_QS + BM1 * VS * 2;      // +8704
constexpr int LDS1   = OFF_KS + BM1 * VS * 2;      // 33792 bytes -> 4 blocks/CU

typedef __attribute__((ext_vector_type(8))) short short8;       // 8 bf16
typedef __attribute__((ext_vector_type(4))) float f32x4;
typedef __attribute__((ext_vector_type(2))) float f32x2;
typedef __attribute__((ext_vector_type(2))) unsigned short us2;

__device__ __forceinline__ unsigned short f2bf(float f) {   // RNE fp32->bf16
    unsigned int u = __float_as_uint(f);
    return (unsigned short)((u + 0x7FFFu + ((u >> 16) & 1u)) >> 16);
}
__device__ __forceinline__ float bf2f(unsigned short u) {
    return __uint_as_float(((unsigned int)u) << 16);
}
// swizzled byte offset in a [rows]x256-bf16 LDS tile (row stride 512B)
__device__ __forceinline__ int swz(int row, int kElem) {
    int b = (row << 9) + (kElem << 1);
    return b ^ ((row & 7) << 4);
}
__device__ __forceinline__ float red16(float v) {  // sum over 16-lane group
    v += __shfl_xor(v, 1); v += __shfl_xor(v, 2);
    v += __shfl_xor(v, 4); v += __shfl_xor(v, 8);
    return v;
}

// ---------------------------------------------------------------------------
// prep: pack Wq|Wk|Wv|Wo (fp32 row-major 256x256) -> bf16, concatenated.
// ---------------------------------------------------------------------------
__global__ __launch_bounds__(256)
void pack_w(const float* __restrict__ Wq, const float* __restrict__ Wk,
            const float* __restrict__ Wv, const float* __restrict__ Wo,
            unsigned short* __restrict__ wbf)
{
    const int i = (blockIdx.x * 256 + threadIdx.x) * 8;
    const float* src = (i < 65536) ? Wq : (i < 131072) ? Wk
                     : (i < 196608) ? Wv : Wo;
    const int off = i & 65535;
    const float4 a = *reinterpret_cast<const float4*>(src + off);
    const float4 b = *reinterpret_cast<const float4*>(src + off + 4);
    short8 p;
    p[0]=(short)f2bf(a.x); p[1]=(short)f2bf(a.y);
    p[2]=(short)f2bf(a.z); p[3]=(short)f2bf(a.w);
    p[4]=(short)f2bf(b.x); p[5]=(short)f2bf(b.y);
    p[6]=(short)f2bf(b.z); p[7]=(short)f2bf(b.w);
    *reinterpret_cast<short8*>(wbf + i) = p;
}

// 16-row x 256-col GEMM: A from swizzled LDS (bf16), W bf16 from global (L2).
__device__ __forceinline__ void gemm16(const unsigned char* As,
                                       const unsigned short* Wg,
                                       int cw, int lrow, int kg8,
                                       f32x4 acc[4])
{
    #pragma unroll
    for (int kk = 0; kk < C_; kk += 32) {
        const short8 af = *reinterpret_cast<const short8*>(As + swz(lrow, kk + kg8));
        #pragma unroll
        for (int j = 0; j < 4; ++j) {
            const short8 bf = *reinterpret_cast<const short8*>(
                Wg + (size_t)(cw + j*16 + lrow) * C_ + kk + kg8);
            acc[j] = __builtin_amdgcn_mfma_f32_16x16x32_bf16(af, bf, acc[j], 0, 0, 0);
        }
    }
}

// ---------------------------------------------------------------------------
// Kernel 1: fused q/k/v projections + head-axis attention, 16 rows/block.
// q/k/v staged in LDS as bf16 (33 KB total -> 4 blocks/CU). k and v GEMMs
// share one K-loop (same A-tile, two W streams). Pos loads prefetched.
// attn out -> bf16 flat (B,H,N,D): b*230400 + h*28800 + n*32 + d.
// ---------------------------------------------------------------------------
__global__ __launch_bounds__(256, 4)
void fused_qkva(const float* __restrict__ query, const float* __restrict__ key,
                const float* __restrict__ qpos,  const float* __restrict__ kpos,
                const unsigned short* __restrict__ wbf,
                const float* __restrict__ bq, const float* __restrict__ bk,
                const float* __restrict__ bv,
                unsigned short* __restrict__ abf)
{
    extern __shared__ char smem[];
    unsigned char* Aq = (unsigned char*)smem;            // 8 KB
    unsigned char* Ak = (unsigned char*)smem + 8192;     // 8 KB
    unsigned short* q_sb = (unsigned short*)(smem + OFF_QS);  // [16][272] bf16
    unsigned short* k_sb = (unsigned short*)(smem + OFF_KS);
    unsigned short* v_sb = (unsigned short*)smem;        // overlays staging

    const int tid = threadIdx.x;
    const int r0  = blockIdx.x * BM1;

    // ---- phase 0: stage query/key rows -> bf16 swizzled LDS ----
    {
        const int trow = tid >> 5, k0 = (tid & 31) * 8;
        #pragma unroll
        for (int i = 0; i < 2; ++i) {
            const int row = trow + i * 8;
            const float* xr = query + (size_t)(r0 + row) * C_ + k0;
            const float4 a0 = *reinterpret_cast<const float4*>(xr);
            const float4 a1 = *reinterpret_cast<const float4*>(xr + 4);
            short8 pa;
            pa[0]=(short)f2bf(a0.x); pa[1]=(short)f2bf(a0.y);
            pa[2]=(short)f2bf(a0.z); pa[3]=(short)f2bf(a0.w);
            pa[4]=(short)f2bf(a1.x); pa[5]=(short)f2bf(a1.y);
            pa[6]=(short)f2bf(a1.z); pa[7]=(short)f2bf(a1.w);
            *reinterpret_cast<short8*>(Aq + swz(row, k0)) = pa;
            const float* kr = key + (size_t)(r0 + row) * C_ + k0;
            const float4 b0 = *reinterpret_cast<const float4*>(kr);
            const float4 b1 = *reinterpret_cast<const float4*>(kr + 4);
            short8 pb;
            pb[0]=(short)f2bf(b0.x); pb[1]=(short)f2bf(b0.y);
            pb[2]=(short)f2bf(b0.z); pb[3]=(short)f2bf(b0.w);
            pb[4]=(short)f2bf(b1.x); pb[5]=(short)f2bf(b1.y);
            pb[6]=(short)f2bf(b1.z); pb[7]=(short)f2bf(b1.w);
            *reinterpret_cast<short8*>(Ak + swz(row, k0)) = pb;
        }
    }
    __syncthreads();

    const int wave = tid >> 6, lane = tid & 63;
    const int cw = wave * 64;
    const int lrow = lane & 15, kg8 = (lane >> 4) * 8;
    const int crow0 = (lane >> 4) * 4, ccol = lane & 15;

    int grs[4];
    #pragma unroll
    for (int r_ = 0; r_ < 4; ++r_) grs[r_] = r0 + crow0 + r_;

    // prefetch qpos values needed by the q epilogue (hide under q K-loop)
    float qp[16];
    #pragma unroll
    for (int j = 0; j < 4; ++j)
        #pragma unroll
        for (int r_ = 0; r_ < 4; ++r_)
            qp[j*4+r_] = qpos[(size_t)grs[r_] * C_ + cw + j*16 + ccol];

    // ---- q GEMM ----
    f32x4 qa[4] = {};
    gemm16(Aq, wbf + 0*65536, cw, lrow, kg8, qa);

    // prefetch kpos (hide under kv K-loop)
    float kp[16];
    #pragma unroll
    for (int j = 0; j < 4; ++j)
        #pragma unroll
        for (int r_ = 0; r_ < 4; ++r_)
            kp[j*4+r_] = kpos[(size_t)grs[r_] * C_ + cw + j*16 + ccol];

    // q epilogue -> q_sb (bf16, post-sigmoid)
    #pragma unroll
    for (int j = 0; j < 4; ++j) {
        const int ch = cw + j*16 + ccol;
        const float bias_v = bq[ch];
        #pragma unroll
        for (int r_ = 0; r_ < 4; ++r_) {
            float v = qa[j][r_] + bias_v + qp[j*4+r_];
            q_sb[(crow0 + r_)*VS + ch] = f2bf(1.f / (1.f + expf(-v)));
        }
    }

    // ---- fused k+v GEMM: one A-tile read, two W streams, 8 MFMA/step ----
    f32x4 ka[4] = {}, va[4] = {};
    {
        const unsigned short* Wk_ = wbf + 1*65536;
        const unsigned short* Wv_ = wbf + 2*65536;
        #pragma unroll
        for (int kk = 0; kk < C_; kk += 32) {
            const short8 af = *reinterpret_cast<const short8*>(Ak + swz(lrow, kk + kg8));
            #pragma unroll
            for (int j = 0; j < 4; ++j) {
                const size_t wo = (size_t)(cw + j*16 + lrow) * C_ + kk + kg8;
                const short8 bkf = *reinterpret_cast<const short8*>(Wk_ + wo);
                const short8 bvf = *reinterpret_cast<const short8*>(Wv_ + wo);
                ka[j] = __builtin_amdgcn_mfma_f32_16x16x32_bf16(af, bkf, ka[j], 0, 0, 0);
                va[j] = __builtin_amdgcn_mfma_f32_16x16x32_bf16(af, bvf, va[j], 0, 0, 0);
            }
        }
    }

    // k epilogue -> k_sb (own region, safe pre-barrier)
    #pragma unroll
    for (int j = 0; j < 4; ++j) {
        const int ch = cw + j*16 + ccol;
        const float bias_v = bk[ch];
        #pragma unroll
        for (int r_ = 0; r_ < 4; ++r_) {
            float v = ka[j][r_] + bias_v + kp[j*4+r_];
            k_sb[(crow0 + r_)*VS + ch] = f2bf(1.f / (1.f + expf(-v)));
        }
    }
    __syncthreads();   // all waves done reading Aq/Ak -> staging reusable

    // v epilogue -> v_sb (overlays staging region)
    #pragma unroll
    for (int j = 0; j < 4; ++j) {
        const int ch = cw + j*16 + ccol;
        const float bias_v = bv[ch];
        #pragma unroll
        for (int r_ = 0; r_ < 4; ++r_)
            v_sb[(crow0 + r_)*VS + ch] = f2bf(va[j][r_] + bias_v);
    }
    __syncthreads();

    // ---- phase 2: per-location attention, 16 threads/location ----
    {
        const int loc = tid >> 4, tt = tid & 15, d0 = tt * 2;
        const int gr = r0 + loc;                 // global row in (n,b) order
        const int nn = gr >> 3, bb = gr & 7;
        const unsigned short* qr = q_sb + loc * VS + d0;
        const unsigned short* kr = k_sb + loc * VS + d0;
        const unsigned short* vr = v_sb + loc * VS + d0;
        f32x2 qh[8], kh[8], vh[8];
        #pragma unroll
        for (int h = 0; h < 8; ++h) {
            const us2 tq = *reinterpret_cast<const us2*>(qr + (h << 5));
            const us2 tk = *reinterpret_cast<const us2*>(kr + (h << 5));
            const us2 tv = *reinterpret_cast<const us2*>(vr + (h << 5));
            qh[h][0] = bf2f(tq[0]); qh[h][1] = bf2f(tq[1]);
            kh[h][0] = bf2f(tk[0]); kh[h][1] = bf2f(tk[1]);
            vh[h][0] = bf2f(tv[0]); vh[h][1] = bf2f(tv[1]);
        }

        float ir1[8], so_[8];
        {
            f32x2 ck = {0,0}, cq = {0,0};
            #pragma unroll
            for (int h = 0; h < 8; ++h) {
                float p1 = 0.f, p2 = 0.f;
                #pragma unroll
                for (int j = 0; j < 2; ++j) {
                    ck[j] += kh[h][j]; cq[j] += qh[h][j];
                    p1 += (qh[h][j] + EPSV) * (ck[j] + EPSV);
                    p2 += (kh[h][j] + EPSV) * (cq[j] + EPSV);
                }
                p1 = red16(p1); p2 = red16(p2);
                ir1[h] = 1.f / p1;
                so_[h] = (float)(h+1) / p2;
            }
        }
        float salloc[8], scomp[8];
        {
            f32x2 c2 = {0,0}, c3 = {0,0};
            float css = 0.f;
            #pragma unroll
            for (int h = 0; h < 8; ++h) {
                const float sih = (float)(h+1) * ir1[h];
                float p3 = 0.f, p4 = 0.f;
                #pragma unroll
                for (int j = 0; j < 2; ++j) {
                    c2[j] += kh[h][j] * so_[h];
                    c3[j] += qh[h][j] * sih;
                    p3 += (qh[h][j] + EPSV) * (c2[j] + EPSV);
                    p4 += (kh[h][j] + EPSV) * (c3[j] + EPSV);
                }
                p3 = red16(p3); p4 = red16(p4);
                const float inv_n = 1.f / (float)(h+1);
                salloc[h] = 1.f / (1.f + expf(-p3 * inv_n));
                const float consrc = fminf(1.f, fmaxf(-1.f, p4 * inv_n));
                const float cs = expf(consrc);
                css += cs;
                scomp[h] = cs / css * (float)(h+1);
            }
        }
        #pragma unroll
        for (int h = 0; h < 8; ++h) {
            f32x2 qs2, a2 = {0,0};
            #pragma unroll
            for (int j = 0; j < 2; ++j) qs2[j] = qh[h][j] * ir1[h];
            #pragma unroll
            for (int h2 = 0; h2 <= h; ++h2) {
                float p = 0.f;
                #pragma unroll
                for (int j = 0; j < 2; ++j) p += qs2[j] * kh[h2][j];
                p = red16(p);
                const float w = p * scomp[h2];
                #pragma unroll
                for (int j = 0; j < 2; ++j) a2[j] += w * vh[h2][j];
            }
            us2 o;
            o[0] = f2bf(a2[0] * salloc[h]);
            o[1] = f2bf(a2[1] * salloc[h]);
            *reinterpret_cast<us2*>(abf + (size_t)bb*(H_*N_*D_) + (size_t)h*(N_*D_)
                                        + (size_t)nn*D_ + d0) = o;
        }
    }
}

// ---------------------------------------------------------------------------
// Kernel 2: out-projection + residual. Block = 32 rows x 64 cols (225x4 grid,
// 900 blocks). A rows are the SCRAMBLED flat slices of abf.
// ---------------------------------------------------------------------------
__global__ __launch_bounds__(256, 4)
void outproj(const unsigned short* __restrict__ abf,
             const unsigned short* __restrict__ wbf,
             const float* __restrict__ bo,
             const float* __restrict__ query,
             float* __restrict__ out)
{
    __shared__ unsigned char As[16384];
    const int tid = threadIdx.x;
    const int r0  = blockIdx.x * BM2;
    const int c0  = blockIdx.y * 64;

    {   // stage scrambled A rows (pure bf16 copy)
        const int trow = tid >> 5, k0 = (tid & 31) * 8;
        #pragma unroll
        for (int i = 0; i < 4; ++i) {
            const int row = trow + i * 8;
            const int gr = r0 + row;
            const int nn = gr >> 3, bb = gr & 7;
            const short8 p = *reinterpret_cast<const short8*>(
                abf + (size_t)bb * (N_*C_) + (size_t)nn * C_ + k0);
            *reinterpret_cast<short8*>(As + swz(row, k0)) = p;
        }
    }
    __syncthreads();

    const int wave = tid >> 6, lane = tid & 63;
    const int rh = (wave & 1) * 16;            // row-half of the 32-row tile
    const int cw = c0 + (wave >> 1) * 32;      // 32-col slice
    const int lrow = lane & 15, kg8 = (lane >> 4) * 8;
    const int crow0 = (lane >> 4) * 4, ccol = lane & 15;
    const unsigned short* Wg = wbf + 3*65536;

    f32x4 acc[2] = {};
    #pragma unroll
    for (int kk = 0; kk < C_; kk += 32) {
        const short8 af = *reinterpret_cast<const short8*>(As + swz(rh + lrow, kk + kg8));
        #pragma unroll
        for (int j = 0; j < 2; ++j) {
            const short8 bf = *reinterpret_cast<const short8*>(
                Wg + (size_t)(cw + j*16 + lrow) * C_ + kk + kg8);
            acc[j] = __builtin_amdgcn_mfma_f32_16x16x32_bf16(af, bf, acc[j], 0, 0, 0);
        }
    }

    #pragma unroll
    for (int j = 0; j < 2; ++j) {
        const int ch = cw + j*16 + ccol;
        const float bias_v = bo[ch];
        #pragma unroll
        for (int r_ = 0; r_ < 4; ++r_) {
            const int row = rh + crow0 + r_;
            const size_t g = (size_t)(r0 + row) * C_ + ch;
            out[g] = acc[j][r_] + bias_v + query[g];
        }
    }
}

// ---------------------------------------------------------------------------
extern "C" void kernel_launch(void* const* d_in, const int* in_sizes, int n_in,
                              void* d_out, int out_size, void* d_ws, size_t ws_size,
                              hipStream_t stream)
{
    const float* query = (const float*)d_in[0];
    const float* key   = (const float*)d_in[1];
    const float* qpos  = (const float*)d_in[2];
    const float* kpos  = (const float*)d_in[3];
    const float* Wq = (const float*)d_in[4];  const float* bq = (const float*)d_in[5];
    const float* Wk = (const float*)d_in[6];  const float* bk = (const float*)d_in[7];
    const float* Wv = (const float*)d_in[8];  const float* bv = (const float*)d_in[9];
    const float* Wo = (const float*)d_in[10]; const float* bo = (const float*)d_in[11];

    unsigned short* wbf = (unsigned short*)d_ws;        // 4*65536 bf16 = 512 KB
    unsigned short* abf = wbf + 4*65536;                // B*N*C bf16 = 3.7 MB
    float* out = (float*)d_out;

    pack_w<<<128, 256, 0, stream>>>(Wq, Wk, Wv, Wo, wbf);
    fused_qkva<<<NBLK1, 256, LDS1, stream>>>(query, key, qpos, kpos, wbf,
                                             bq, bk, bv, abf);
    outproj<<<dim3(NBLK2, 4), 256, 0, stream>>>(abf, wbf, bo, query, out);
}

// Round 9
// 46.369 us; speedup vs baseline: 3.4809x; 1.2757x over previous
//
#include <hip/hip_runtime.h>
#include <math.h>

#define EPSV 1e-6f
constexpr int N_ = 900, B_ = 8, C_ = 256, H_ = 8, D_ = 32;
constexpr int M_TOT = N_ * B_;        // 7200 rows
constexpr int BM  = 32;               // rows per block, kernel 1
constexpr int NBLK = M_TOT / BM;      // 225 blocks
constexpr int BM2 = 32;               // rows per block, kernel 2
constexpr int NBLK2 = M_TOT / BM2;    // 225 row-blocks (x4 col-quarters)
constexpr int VS  = 272;              // q/k/v LDS row stride (shorts)
// kernel-1 LDS: Wslice dbuf 64K | Aq 16K | Ak 16K | q/k/v bf16 3x17K
constexpr int OFF_AQ = 65536;
constexpr int OFF_AK = 81920;
constexpr int OFF_Q  = 98304;
constexpr int OFF_K  = OFF_Q + BM * VS * 2;    // 115712
constexpr int OFF_V  = OFF_K + BM * VS * 2;    // 133120
constexpr int LDS1   = OFF_V + BM * VS * 2;    // 150528 bytes

typedef __attribute__((ext_vector_type(8))) short short8;       // 8 bf16
typedef __attribute__((ext_vector_type(4))) float f32x4;
typedef __attribute__((ext_vector_type(4))) unsigned short us4;

__device__ __forceinline__ unsigned short f2bf(float f) {   // RNE fp32->bf16
    unsigned int u = __float_as_uint(f);
    return (unsigned short)((u + 0x7FFFu + ((u >> 16) & 1u)) >> 16);
}
__device__ __forceinline__ float bf2f(unsigned short u) {
    return __uint_as_float(((unsigned int)u) << 16);
}
// swizzled byte offset in a [rows]x256-bf16 LDS tile (row stride 512B)
__device__ __forceinline__ int swz(int row, int kElem) {
    int b = (row << 9) + (kElem << 1);
    return b ^ ((row & 7) << 4);
}
__device__ __forceinline__ float red8(float v) {   // sum over 8-lane group
    v += __shfl_xor(v, 1); v += __shfl_xor(v, 2); v += __shfl_xor(v, 4);
    return v;
}
__device__ __forceinline__ void fence() { asm volatile("" ::: "memory"); }

// ---------------------------------------------------------------------------
// prep: pack Wq|Wk|Wv|Wo (fp32 row-major 256x256) -> bf16, concatenated.
// ---------------------------------------------------------------------------
__global__ __launch_bounds__(256)
void pack_w(const float* __restrict__ Wq, const float* __restrict__ Wk,
            const float* __restrict__ Wv, const float* __restrict__ Wo,
            unsigned short* __restrict__ wbf)
{
    const int i = (blockIdx.x * 256 + threadIdx.x) * 8;
    const float* src = (i < 65536) ? Wq : (i < 131072) ? Wk
                     : (i < 196608) ? Wv : Wo;
    const int off = i & 65535;
    const float4 a = *reinterpret_cast<const float4*>(src + off);
    const float4 b = *reinterpret_cast<const float4*>(src + off + 4);
    short8 p;
    p[0]=(short)f2bf(a.x); p[1]=(short)f2bf(a.y);
    p[2]=(short)f2bf(a.z); p[3]=(short)f2bf(a.w);
    p[4]=(short)f2bf(b.x); p[5]=(short)f2bf(b.y);
    p[6]=(short)f2bf(b.z); p[7]=(short)f2bf(b.w);
    *reinterpret_cast<short8*>(wbf + i) = p;
}

// ---------------------------------------------------------------------------
// Async-DMA stage of one W K-slice (256 cols x 64 k, bf16, 32 KB) into LDS.
// LDS dest is linear (DMA writes base + lane*16); the st-swizzle
// byte ^= ((col&7)<<4) is applied by PRE-SWIZZLING the per-lane global src.
// 8 issues per wave x 4 waves x 64 lanes x 16B = 32 KB.
// ---------------------------------------------------------------------------
__device__ __forceinline__ void stageW(const unsigned short* Wmat, int kkElem,
                                       char* wbufLds, int wave, int lane)
{
    #pragma unroll
    for (int n = 0; n < 8; ++n) {
        const int idx = wave * 8 + n;
        const int Lr  = idx * 1024 + lane * 16;          // linear LDS byte
        const int col = Lr >> 7;                          // 128B per col-row
        const int kb  = (Lr & 127) ^ ((col & 7) << 4);    // inverse swizzle
        const char* src = (const char*)Wmat + col * 512 + kkElem * 2 + kb;
        __builtin_amdgcn_global_load_lds(
            (const __attribute__((address_space(1))) unsigned int*)src,
            (__attribute__((address_space(3))) unsigned int*)(wbufLds + idx * 1024),
            16, 0, 0);
    }
}

// one pipeline step: 4 A ds_reads + 8 swizzled W ds_reads + 16 MFMA
__device__ __forceinline__ void step_mm(const unsigned char* At, const char* wb,
                                        int kkA, int cw, int lrow, int kg8,
                                        f32x4 acc[2][4])
{
    #pragma unroll
    for (int kh = 0; kh < 2; ++kh) {
        const short8 a0 = *reinterpret_cast<const short8*>(At + swz(lrow,      kkA + kh*32 + kg8));
        const short8 a1 = *reinterpret_cast<const short8*>(At + swz(16 + lrow, kkA + kh*32 + kg8));
        #pragma unroll
        for (int j = 0; j < 4; ++j) {
            const int col = cw + j*16 + lrow;
            const short8 bfr = *reinterpret_cast<const short8*>(
                wb + col*128 + ((kh*64 + kg8*2) ^ ((col & 7) << 4)));
            acc[0][j] = __builtin_amdgcn_mfma_f32_16x16x32_bf16(a0, bfr, acc[0][j], 0, 0, 0);
            acc[1][j] = __builtin_amdgcn_mfma_f32_16x16x32_bf16(a1, bfr, acc[1][j], 0, 0, 0);
        }
    }
}

// ---------------------------------------------------------------------------
// Kernel 1: fused q/k/v projections + head-axis attention, 32 rows/block.
// Unified 12-step K-loop (Wq 0-3, Wk 4-7, Wv 8-11), W slices via async
// global_load_lds double-buffer with counted vmcnt(8).
// attn out -> bf16 flat (B,H,N,D): b*230400 + h*28800 + n*32 + d.
// ---------------------------------------------------------------------------
__global__ __launch_bounds__(256)
void fused_qkva(const float* __restrict__ query, const float* __restrict__ key,
                const float* __restrict__ qpos,  const float* __restrict__ kpos,
                const unsigned short* __restrict__ wbf,
                const float* __restrict__ bq, const float* __restrict__ bk,
                const float* __restrict__ bv,
                unsigned short* __restrict__ abf)
{
    extern __shared__ char smem[];
    char* Wb = smem;                                      // 2 x 32 KB slices
    unsigned char* Aq = (unsigned char*)(smem + OFF_AQ);  // 16 KB
    unsigned char* Ak = (unsigned char*)(smem + OFF_AK);  // 16 KB
    unsigned short* q_sb = (unsigned short*)(smem + OFF_Q);   // [32][272] bf16
    unsigned short* k_sb = (unsigned short*)(smem + OFF_K);
    unsigned short* v_sb = (unsigned short*)(smem + OFF_V);

    const int tid = threadIdx.x;
    const int r0  = blockIdx.x * BM;
    const int wave = tid >> 6, lane = tid & 63;

    // ---- prologue: DMA slice 0 of Wq, then register-stage A tiles ----
    stageW(wbf, 0, Wb, wave, lane);

    {
        const int trow = tid >> 5, k0 = (tid & 31) * 8;
        #pragma unroll
        for (int i = 0; i < 4; ++i) {
            const int row = trow + i * 8;
            const float* xr = query + (size_t)(r0 + row) * C_ + k0;
            const float4 a0 = *reinterpret_cast<const float4*>(xr);
            const float4 a1 = *reinterpret_cast<const float4*>(xr + 4);
            short8 pa;
            pa[0]=(short)f2bf(a0.x); pa[1]=(short)f2bf(a0.y);
            pa[2]=(short)f2bf(a0.z); pa[3]=(short)f2bf(a0.w);
            pa[4]=(short)f2bf(a1.x); pa[5]=(short)f2bf(a1.y);
            pa[6]=(short)f2bf(a1.z); pa[7]=(short)f2bf(a1.w);
            *reinterpret_cast<short8*>(Aq + swz(row, k0)) = pa;
            const float* kr = key + (size_t)(r0 + row) * C_ + k0;
            const float4 b0 = *reinterpret_cast<const float4*>(kr);
            const float4 b1 = *reinterpret_cast<const float4*>(kr + 4);
            short8 pb;
            pb[0]=(short)f2bf(b0.x); pb[1]=(short)f2bf(b0.y);
            pb[2]=(short)f2bf(b0.z); pb[3]=(short)f2bf(b0.w);
            pb[4]=(short)f2bf(b1.x); pb[5]=(short)f2bf(b1.y);
            pb[6]=(short)f2bf(b1.z); pb[7]=(short)f2bf(b1.w);
            *reinterpret_cast<short8*>(Ak + swz(row, k0)) = pb;
        }
    }

    const int cw = wave * 64;
    const int lrow = lane & 15, kg8 = (lane >> 4) * 8;
    const int crow0 = (lane >> 4) * 4, ccol = lane & 15;

    // ---- prefetch pos + biases (retire during prologue drain) ----
    float qp[32], kp[32], bqv[4], bkv[4], bvv[4];
    #pragma unroll
    for (int j = 0; j < 4; ++j) {
        const int ch = cw + j*16 + ccol;
        bqv[j] = bq[ch]; bkv[j] = bk[ch]; bvv[j] = bv[ch];
        #pragma unroll
        for (int rh = 0; rh < 2; ++rh)
            #pragma unroll
            for (int r_ = 0; r_ < 4; ++r_) {
                const int gr = r0 + rh*16 + crow0 + r_;
                qp[j*8+rh*4+r_] = qpos[(size_t)gr * C_ + ch];
                kp[j*8+rh*4+r_] = kpos[(size_t)gr * C_ + ch];
            }
    }

    __syncthreads();   // full drain: slice 0 + A ds_writes + prefetch loads

    // ---- 12-step pipelined K-loop ----
    f32x4 qacc[2][4] = {}; f32x4 kacc[2][4] = {}; f32x4 vacc[2][4] = {};

    #pragma unroll
    for (int s = 0; s < 12; ++s) {
        if (s < 11) {
            const int nx = s + 1;
            stageW(wbf + (nx >> 2) * 65536, (nx & 3) * 64,
                   Wb + (nx & 1) * 32768, wave, lane);
            asm volatile("s_waitcnt vmcnt(8) lgkmcnt(0)" ::: "memory");
        } else {
            asm volatile("s_waitcnt vmcnt(0) lgkmcnt(0)" ::: "memory");
        }
        __builtin_amdgcn_s_barrier();
        fence();

        const char* wb = Wb + (s & 1) * 32768;
        const int kkA = (s & 3) * 64;
        if (s < 4)      step_mm(Aq, wb, kkA, cw, lrow, kg8, qacc);
        else if (s < 8) step_mm(Ak, wb, kkA, cw, lrow, kg8, kacc);
        else            step_mm(Ak, wb, kkA, cw, lrow, kg8, vacc);

        if (s == 3) {   // q epilogue -> q_sb (bf16, sigmoid)
            #pragma unroll
            for (int j = 0; j < 4; ++j) {
                const int ch = cw + j*16 + ccol;
                #pragma unroll
                for (int rh = 0; rh < 2; ++rh)
                    #pragma unroll
                    for (int r_ = 0; r_ < 4; ++r_) {
                        float v = qacc[rh][j][r_] + bqv[j] + qp[j*8+rh*4+r_];
                        q_sb[(rh*16+crow0+r_)*VS + ch] = f2bf(1.f/(1.f+expf(-v)));
                    }
            }
        }
        if (s == 7) {   // k epilogue
            #pragma unroll
            for (int j = 0; j < 4; ++j) {
                const int ch = cw + j*16 + ccol;
                #pragma unroll
                for (int rh = 0; rh < 2; ++rh)
                    #pragma unroll
                    for (int r_ = 0; r_ < 4; ++r_) {
                        float v = kacc[rh][j][r_] + bkv[j] + kp[j*8+rh*4+r_];
                        k_sb[(rh*16+crow0+r_)*VS + ch] = f2bf(1.f/(1.f+expf(-v)));
                    }
            }
        }
        if (s == 11) {  // v epilogue (no pos, no sigmoid)
            #pragma unroll
            for (int j = 0; j < 4; ++j) {
                const int ch = cw + j*16 + ccol;
                #pragma unroll
                for (int rh = 0; rh < 2; ++rh)
                    #pragma unroll
                    for (int r_ = 0; r_ < 4; ++r_)
                        v_sb[(rh*16+crow0+r_)*VS + ch] =
                            f2bf(vacc[rh][j][r_] + bvv[j]);
            }
        }

        asm volatile("s_waitcnt lgkmcnt(0)" ::: "memory");
        __builtin_amdgcn_s_barrier();
        fence();
    }

    // ---- attention: 8 threads/location, 32 locations ----
    {
        const int loc = tid >> 3, tt = tid & 7, d0 = tt * 4;
        const int gr = r0 + loc;                 // global row in (n,b) order
        const int nn = gr >> 3, bb = gr & 7;
        const unsigned short* qr = q_sb + loc * VS + d0;
        const unsigned short* kr = k_sb + loc * VS + d0;
        const unsigned short* vr = v_sb + loc * VS + d0;
        f32x4 qh[8], kh[8], vh[8];
        #pragma unroll
        for (int h = 0; h < 8; ++h) {
            const us4 tq = *reinterpret_cast<const us4*>(qr + (h << 5));
            const us4 tk = *reinterpret_cast<const us4*>(kr + (h << 5));
            const us4 tv = *reinterpret_cast<const us4*>(vr + (h << 5));
            #pragma unroll
            for (int j = 0; j < 4; ++j) {
                qh[h][j] = bf2f(tq[j]); kh[h][j] = bf2f(tk[j]); vh[h][j] = bf2f(tv[j]);
            }
        }

        float ir1[8], so_[8];
        {
            f32x4 ck = {0,0,0,0}, cq = {0,0,0,0};
            #pragma unroll
            for (int h = 0; h < 8; ++h) {
                float p1 = 0.f, p2 = 0.f;
                #pragma unroll
                for (int j = 0; j < 4; ++j) {
                    ck[j] += kh[h][j]; cq[j] += qh[h][j];
                    p1 += (qh[h][j] + EPSV) * (ck[j] + EPSV);
                    p2 += (kh[h][j] + EPSV) * (cq[j] + EPSV);
                }
                p1 = red8(p1); p2 = red8(p2);
                ir1[h] = 1.f / p1;
                so_[h] = (float)(h+1) / p2;
            }
        }
        float salloc[8], scomp[8];
        {
            f32x4 c2 = {0,0,0,0}, c3 = {0,0,0,0};
            float css = 0.f;
            #pragma unroll
            for (int h = 0; h < 8; ++h) {
                const float sih = (float)(h+1) * ir1[h];
                float p3 = 0.f, p4 = 0.f;
                #pragma unroll
                for (int j = 0; j < 4; ++j) {
                    c2[j] += kh[h][j] * so_[h];
                    c3[j] += qh[h][j] * sih;
                    p3 += (qh[h][j] + EPSV) * (c2[j] + EPSV);
                    p4 += (kh[h][j] + EPSV) * (c3[j] + EPSV);
                }
                p3 = red8(p3); p4 = red8(p4);
                const float inv_n = 1.f / (float)(h+1);
                salloc[h] = 1.f / (1.f + expf(-p3 * inv_n));
                const float consrc = fminf(1.f, fmaxf(-1.f, p4 * inv_n));
                const float cs = expf(consrc);
                css += cs;
                scomp[h] = cs / css * (float)(h+1);
            }
        }
        #pragma unroll
        for (int h = 0; h < 8; ++h) {
            f32x4 qs4, a4 = {0,0,0,0};
            #pragma unroll
            for (int j = 0; j < 4; ++j) qs4[j] = qh[h][j] * ir1[h];
            #pragma unroll
            for (int h2 = 0; h2 <= h; ++h2) {
                float p = 0.f;
                #pragma unroll
                for (int j = 0; j < 4; ++j) p += qs4[j] * kh[h2][j];
                p = red8(p);
                const float w = p * scomp[h2];
                #pragma unroll
                for (int j = 0; j < 4; ++j) a4[j] += w * vh[h2][j];
            }
            us4 o;
            #pragma unroll
            for (int j = 0; j < 4; ++j) o[j] = f2bf(a4[j] * salloc[h]);
            *reinterpret_cast<us4*>(abf + (size_t)bb*(H_*N_*D_) + (size_t)h*(N_*D_)
                                        + (size_t)nn*D_ + d0) = o;
        }
    }
}

// ---------------------------------------------------------------------------
// Kernel 2: out-projection + residual. Block = 32 rows x 64 cols (225x4 grid).
// A rows are the SCRAMBLED flat slices of abf.
// ---------------------------------------------------------------------------
__global__ __launch_bounds__(256, 4)
void outproj(const unsigned short* __restrict__ abf,
             const unsigned short* __restrict__ wbf,
             const float* __restrict__ bo,
             const float* __restrict__ query,
             float* __restrict__ out)
{
    __shared__ unsigned char As[16384];
    const int tid = threadIdx.x;
    const int r0  = blockIdx.x * BM2;
    const int c0  = blockIdx.y * 64;

    {   // stage scrambled A rows (pure bf16 copy)
        const int trow = tid >> 5, k0 = (tid & 31) * 8;
        #pragma unroll
        for (int i = 0; i < 4; ++i) {
            const int row = trow + i * 8;
            const int gr = r0 + row;
            const int nn = gr >> 3, bb = gr & 7;
            const short8 p = *reinterpret_cast<const short8*>(
                abf + (size_t)bb * (N_*C_) + (size_t)nn * C_ + k0);
            *reinterpret_cast<short8*>(As + swz(row, k0)) = p;
        }
    }
    __syncthreads();

    const int wave = tid >> 6, lane = tid & 63;
    const int rh = (wave & 1) * 16;            // row-half of the 32-row tile
    const int cw = c0 + (wave >> 1) * 32;      // 32-col slice
    const int lrow = lane & 15, kg8 = (lane >> 4) * 8;
    const int crow0 = (lane >> 4) * 4, ccol = lane & 15;
    const unsigned short* Wg = wbf + 3*65536;

    f32x4 acc[2] = {};
    #pragma unroll
    for (int kk = 0; kk < C_; kk += 32) {
        const short8 af = *reinterpret_cast<const short8*>(As + swz(rh + lrow, kk + kg8));
        #pragma unroll
        for (int j = 0; j < 2; ++j) {
            const short8 bf = *reinterpret_cast<const short8*>(
                Wg + (size_t)(cw + j*16 + lrow) * C_ + kk + kg8);
            acc[j] = __builtin_amdgcn_mfma_f32_16x16x32_bf16(af, bf, acc[j], 0, 0, 0);
        }
    }

    #pragma unroll
    for (int j = 0; j < 2; ++j) {
        const int ch = cw + j*16 + ccol;
        const float bias_v = bo[ch];
        #pragma unroll
        for (int r_ = 0; r_ < 4; ++r_) {
            const int row = rh + crow0 + r_;
            const size_t g = (size_t)(r0 + row) * C_ + ch;
            out[g] = acc[j][r_] + bias_v + query[g];
        }
    }
}

// ---------------------------------------------------------------------------
extern "C" void kernel_launch(void* const* d_in, const int* in_sizes, int n_in,
                              void* d_out, int out_size, void* d_ws, size_t ws_size,
                              hipStream_t stream)
{
    const float* query = (const float*)d_in[0];
    const float* key   = (const float*)d_in[1];
    const float* qpos  = (const float*)d_in[2];
    const float* kpos  = (const float*)d_in[3];
    const float* Wq = (const float*)d_in[4];  const float* bq = (const float*)d_in[5];
    const float* Wk = (const float*)d_in[6];  const float* bk = (const float*)d_in[7];
    const float* Wv = (const float*)d_in[8];  const float* bv = (const float*)d_in[9];
    const float* Wo = (const float*)d_in[10]; const float* bo = (const float*)d_in[11];

    unsigned short* wbf = (unsigned short*)d_ws;        // 4*65536 bf16 = 512 KB
    unsigned short* abf = wbf + 4*65536;                // B*N*C bf16 = 3.7 MB
    float* out = (float*)d_out;

    pack_w<<<128, 256, 0, stream>>>(Wq, Wk, Wv, Wo, wbf);
    fused_qkva<<<NBLK, 256, LDS1, stream>>>(query, key, qpos, kpos, wbf,
                                            bq, bk, bv, abf);
    outproj<<<dim3(NBLK2, 4), 256, 0, stream>>>(abf, wbf, bo, query, out);
}

// Round 10
// 35.791 us; speedup vs baseline: 4.5097x; 1.2956x over previous
//
#include <hip/hip_runtime.h>
#include <math.h>

#define EPSV 1e-6f
constexpr int N_ = 900, B_ = 8, C_ = 256, H_ = 8, D_ = 32;
constexpr int M_TOT = N_ * B_;        // 7200 rows
constexpr int BM  = 32;               // rows per block, kernel 1
constexpr int NBLK = M_TOT / BM;      // 225 blocks
constexpr int BM2 = 32;               // rows per block, kernel 2
constexpr int VS  = 272;              // q/k/v LDS row stride (shorts)
// kernel-1 LDS: W wave-private dbuf 4x16K | Aq 16K | Ak 16K | q/k/v bf16
constexpr int OFF_AQ = 65536;
constexpr int OFF_AK = 81920;
constexpr int OFF_Q  = 98304;
constexpr int OFF_K  = OFF_Q + BM * VS * 2;    // 115712
constexpr int OFF_V  = OFF_K + BM * VS * 2;    // 133120
constexpr int LDS1   = OFF_V + BM * VS * 2;    // 150528 bytes
constexpr int LDS2   = 81920;                  // outproj: 64K W + 16K As

typedef __attribute__((ext_vector_type(8))) short short8;       // 8 bf16
typedef __attribute__((ext_vector_type(4))) float f32x4;
typedef __attribute__((ext_vector_type(4))) unsigned short us4;

__device__ __forceinline__ unsigned short f2bf(float f) {   // RNE fp32->bf16
    unsigned int u = __float_as_uint(f);
    return (unsigned short)((u + 0x7FFFu + ((u >> 16) & 1u)) >> 16);
}
__device__ __forceinline__ float bf2f(unsigned short u) {
    return __uint_as_float(((unsigned int)u) << 16);
}
// swizzled byte offset in a [rows]x256-bf16 LDS tile (row stride 512B)
__device__ __forceinline__ int swz(int row, int kElem) {
    int b = (row << 9) + (kElem << 1);
    return b ^ ((row & 7) << 4);
}
__device__ __forceinline__ float red8(float v) {   // sum over 8-lane group
    v += __shfl_xor(v, 1); v += __shfl_xor(v, 2); v += __shfl_xor(v, 4);
    return v;
}

// ---------------------------------------------------------------------------
// prep: pack Wq|Wk|Wv|Wo (fp32 row-major 256x256) -> bf16, concatenated.
// ---------------------------------------------------------------------------
__global__ __launch_bounds__(256)
void pack_w(const float* __restrict__ Wq, const float* __restrict__ Wk,
            const float* __restrict__ Wv, const float* __restrict__ Wo,
            unsigned short* __restrict__ wbf)
{
    const int i = (blockIdx.x * 256 + threadIdx.x) * 8;
    const float* src = (i < 65536) ? Wq : (i < 131072) ? Wk
                     : (i < 196608) ? Wv : Wo;
    const int off = i & 65535;
    const float4 a = *reinterpret_cast<const float4*>(src + off);
    const float4 b = *reinterpret_cast<const float4*>(src + off + 4);
    short8 p;
    p[0]=(short)f2bf(a.x); p[1]=(short)f2bf(a.y);
    p[2]=(short)f2bf(a.z); p[3]=(short)f2bf(a.w);
    p[4]=(short)f2bf(b.x); p[5]=(short)f2bf(b.y);
    p[6]=(short)f2bf(b.z); p[7]=(short)f2bf(b.w);
    *reinterpret_cast<short8*>(wbf + i) = p;
}

// ---------------------------------------------------------------------------
// WAVE-PRIVATE async-DMA stage of this wave's 64-col x 64-k W slice (8 KB).
// LDS dest linear (DMA: uniform base + lane*16); st-swizzle applied by
// pre-swizzling the per-lane global source address.
// ---------------------------------------------------------------------------
__device__ __forceinline__ void stageW(const unsigned short* Wmat, int kkElem,
                                       char* wbufLds, int cw, int lane)
{
    #pragma unroll
    for (int n = 0; n < 8; ++n) {
        const int L  = n * 1024 + lane * 16;              // 0..8191 local byte
        const int cl = L >> 7;                            // local col 0..63
        const int kb = (L & 127) ^ ((cl & 7) << 4);       // inverse swizzle
        const char* src = (const char*)Wmat + (size_t)(cw + cl) * 512
                        + kkElem * 2 + kb;
        __builtin_amdgcn_global_load_lds(
            (const __attribute__((address_space(1))) unsigned int*)src,
            (__attribute__((address_space(3))) unsigned int*)(wbufLds + n * 1024),
            16, 0, 0);
    }
}

// one step: 4 A ds_reads + 8 swizzled W ds_reads + 16 MFMA (wave-local W buf)
__device__ __forceinline__ void step_mm(const unsigned char* At, const char* wb,
                                        int kkA, int lrow, int kg8,
                                        f32x4 acc[2][4])
{
    #pragma unroll
    for (int kh = 0; kh < 2; ++kh) {
        const short8 a0 = *reinterpret_cast<const short8*>(At + swz(lrow,      kkA + kh*32 + kg8));
        const short8 a1 = *reinterpret_cast<const short8*>(At + swz(16 + lrow, kkA + kh*32 + kg8));
        #pragma unroll
        for (int j = 0; j < 4; ++j) {
            const int cl = j*16 + lrow;                   // local col 0..63
            const short8 bfr = *reinterpret_cast<const short8*>(
                wb + cl*128 + ((kh*64 + kg8*2) ^ ((cl & 7) << 4)));
            acc[0][j] = __builtin_amdgcn_mfma_f32_16x16x32_bf16(a0, bfr, acc[0][j], 0, 0, 0);
            acc[1][j] = __builtin_amdgcn_mfma_f32_16x16x32_bf16(a1, bfr, acc[1][j], 0, 0, 0);
        }
    }
}

// ---------------------------------------------------------------------------
// Kernel 1: fused q/k/v projections + head-axis attention, 32 rows/block.
// 12-step K-loop (Wq 0-3, Wk 4-7, Wv 8-11); W slices via WAVE-PRIVATE
// global_load_lds double-buffer, counted vmcnt(8), NO in-loop barriers.
// attn out -> bf16 flat (B,H,N,D): b*230400 + h*28800 + n*32 + d.
// ---------------------------------------------------------------------------
__global__ __launch_bounds__(256)
void fused_qkva(const float* __restrict__ query, const float* __restrict__ key,
                const float* __restrict__ qpos,  const float* __restrict__ kpos,
                const unsigned short* __restrict__ wbf,
                const float* __restrict__ bq, const float* __restrict__ bk,
                const float* __restrict__ bv,
                unsigned short* __restrict__ abf)
{
    extern __shared__ char smem[];
    char* Wb = smem;                                      // 4 x (2 x 8 KB)
    unsigned char* Aq = (unsigned char*)(smem + OFF_AQ);  // 16 KB
    unsigned char* Ak = (unsigned char*)(smem + OFF_AK);  // 16 KB
    unsigned short* q_sb = (unsigned short*)(smem + OFF_Q);   // [32][272] bf16
    unsigned short* k_sb = (unsigned short*)(smem + OFF_K);
    unsigned short* v_sb = (unsigned short*)(smem + OFF_V);

    const int tid = threadIdx.x;
    const int r0  = blockIdx.x * BM;
    const int wave = tid >> 6, lane = tid & 63;
    const int cw = wave * 64;
    char* mywb = Wb + wave * 16384;                       // wave-private dbuf

    // ---- prologue: DMA slice 0 of Wq, then register-stage A tiles ----
    stageW(wbf, 0, mywb, cw, lane);

    {
        const int trow = tid >> 5, k0 = (tid & 31) * 8;
        #pragma unroll
        for (int i = 0; i < 4; ++i) {
            const int row = trow + i * 8;
            const float* xr = query + (size_t)(r0 + row) * C_ + k0;
            const float4 a0 = *reinterpret_cast<const float4*>(xr);
            const float4 a1 = *reinterpret_cast<const float4*>(xr + 4);
            short8 pa;
            pa[0]=(short)f2bf(a0.x); pa[1]=(short)f2bf(a0.y);
            pa[2]=(short)f2bf(a0.z); pa[3]=(short)f2bf(a0.w);
            pa[4]=(short)f2bf(a1.x); pa[5]=(short)f2bf(a1.y);
            pa[6]=(short)f2bf(a1.z); pa[7]=(short)f2bf(a1.w);
            *reinterpret_cast<short8*>(Aq + swz(row, k0)) = pa;
            const float* kr = key + (size_t)(r0 + row) * C_ + k0;
            const float4 b0 = *reinterpret_cast<const float4*>(kr);
            const float4 b1 = *reinterpret_cast<const float4*>(kr + 4);
            short8 pb;
            pb[0]=(short)f2bf(b0.x); pb[1]=(short)f2bf(b0.y);
            pb[2]=(short)f2bf(b0.z); pb[3]=(short)f2bf(b0.w);
            pb[4]=(short)f2bf(b1.x); pb[5]=(short)f2bf(b1.y);
            pb[6]=(short)f2bf(b1.z); pb[7]=(short)f2bf(b1.w);
            *reinterpret_cast<short8*>(Ak + swz(row, k0)) = pb;
        }
    }

    const int lrow = lane & 15, kg8 = (lane >> 4) * 8;
    const int crow0 = (lane >> 4) * 4, ccol = lane & 15;

    // ---- prefetch pos + biases (retire during prologue drain) ----
    float qp[32], kp[32], bqv[4], bkv[4], bvv[4];
    #pragma unroll
    for (int j = 0; j < 4; ++j) {
        const int ch = cw + j*16 + ccol;
        bqv[j] = bq[ch]; bkv[j] = bk[ch]; bvv[j] = bv[ch];
        #pragma unroll
        for (int rh = 0; rh < 2; ++rh)
            #pragma unroll
            for (int r_ = 0; r_ < 4; ++r_) {
                const int gr = r0 + rh*16 + crow0 + r_;
                qp[j*8+rh*4+r_] = qpos[(size_t)gr * C_ + ch];
                kp[j*8+rh*4+r_] = kpos[(size_t)gr * C_ + ch];
            }
    }

    __syncthreads();   // drains slice-0 DMA + A ds_writes + prefetch loads

    // ---- 12-step pipelined K-loop, barrier-free (wave self-paced) ----
    f32x4 qacc[2][4] = {}; f32x4 kacc[2][4] = {}; f32x4 vacc[2][4] = {};

    #pragma unroll
    for (int s = 0; s < 12; ++s) {
        if (s < 11) {
            const int nx = s + 1;
            stageW(wbf + (nx >> 2) * 65536, (nx & 3) * 64,
                   mywb + (nx & 1) * 8192, cw, lane);
            asm volatile("s_waitcnt vmcnt(8)" ::: "memory");
        } else {
            asm volatile("s_waitcnt vmcnt(0)" ::: "memory");
        }

        const char* wb = mywb + (s & 1) * 8192;
        const int kkA = (s & 3) * 64;
        if (s < 4)      step_mm(Aq, wb, kkA, lrow, kg8, qacc);
        else if (s < 8) step_mm(Ak, wb, kkA, lrow, kg8, kacc);
        else            step_mm(Ak, wb, kkA, lrow, kg8, vacc);

        if (s == 3) {   // q epilogue -> q_sb (bf16, sigmoid)
            #pragma unroll
            for (int j = 0; j < 4; ++j) {
                const int ch = cw + j*16 + ccol;
                #pragma unroll
                for (int rh = 0; rh < 2; ++rh)
                    #pragma unroll
                    for (int r_ = 0; r_ < 4; ++r_) {
                        float v = qacc[rh][j][r_] + bqv[j] + qp[j*8+rh*4+r_];
                        q_sb[(rh*16+crow0+r_)*VS + ch] = f2bf(1.f/(1.f+expf(-v)));
                    }
            }
        }
        if (s == 7) {   // k epilogue
            #pragma unroll
            for (int j = 0; j < 4; ++j) {
                const int ch = cw + j*16 + ccol;
                #pragma unroll
                for (int rh = 0; rh < 2; ++rh)
                    #pragma unroll
                    for (int r_ = 0; r_ < 4; ++r_) {
                        float v = kacc[rh][j][r_] + bkv[j] + kp[j*8+rh*4+r_];
                        k_sb[(rh*16+crow0+r_)*VS + ch] = f2bf(1.f/(1.f+expf(-v)));
                    }
            }
        }
        if (s == 11) {  // v epilogue (no pos, no sigmoid)
            #pragma unroll
            for (int j = 0; j < 4; ++j) {
                const int ch = cw + j*16 + ccol;
                #pragma unroll
                for (int rh = 0; rh < 2; ++rh)
                    #pragma unroll
                    for (int r_ = 0; r_ < 4; ++r_)
                        v_sb[(rh*16+crow0+r_)*VS + ch] =
                            f2bf(vacc[rh][j][r_] + bvv[j]);
            }
        }
    }

    __syncthreads();   // qkv LDS complete

    // ---- attention: 8 threads/location, 32 locations ----
    {
        const int loc = tid >> 3, tt = tid & 7, d0 = tt * 4;
        const int gr = r0 + loc;                 // global row in (n,b) order
        const int nn = gr >> 3, bb = gr & 7;
        const unsigned short* qr = q_sb + loc * VS + d0;
        const unsigned short* kr = k_sb + loc * VS + d0;
        const unsigned short* vr = v_sb + loc * VS + d0;
        f32x4 qh[8], kh[8], vh[8];
        #pragma unroll
        for (int h = 0; h < 8; ++h) {
            const us4 tq = *reinterpret_cast<const us4*>(qr + (h << 5));
            const us4 tk = *reinterpret_cast<const us4*>(kr + (h << 5));
            const us4 tv = *reinterpret_cast<const us4*>(vr + (h << 5));
            #pragma unroll
            for (int j = 0; j < 4; ++j) {
                qh[h][j] = bf2f(tq[j]); kh[h][j] = bf2f(tk[j]); vh[h][j] = bf2f(tv[j]);
            }
        }

        float ir1[8], so_[8];
        {
            f32x4 ck = {0,0,0,0}, cq = {0,0,0,0};
            #pragma unroll
            for (int h = 0; h < 8; ++h) {
                float p1 = 0.f, p2 = 0.f;
                #pragma unroll
                for (int j = 0; j < 4; ++j) {
                    ck[j] += kh[h][j]; cq[j] += qh[h][j];
                    p1 += (qh[h][j] + EPSV) * (ck[j] + EPSV);
                    p2 += (kh[h][j] + EPSV) * (cq[j] + EPSV);
                }
                p1 = red8(p1); p2 = red8(p2);
                ir1[h] = 1.f / p1;
                so_[h] = (float)(h+1) / p2;
            }
        }
        float salloc[8], scomp[8];
        {
            f32x4 c2 = {0,0,0,0}, c3 = {0,0,0,0};
            float css = 0.f;
            #pragma unroll
            for (int h = 0; h < 8; ++h) {
                const float sih = (float)(h+1) * ir1[h];
                float p3 = 0.f, p4 = 0.f;
                #pragma unroll
                for (int j = 0; j < 4; ++j) {
                    c2[j] += kh[h][j] * so_[h];
                    c3[j] += qh[h][j] * sih;
                    p3 += (qh[h][j] + EPSV) * (c2[j] + EPSV);
                    p4 += (kh[h][j] + EPSV) * (c3[j] + EPSV);
                }
                p3 = red8(p3); p4 = red8(p4);
                const float inv_n = 1.f / (float)(h+1);
                salloc[h] = 1.f / (1.f + expf(-p3 * inv_n));
                const float consrc = fminf(1.f, fmaxf(-1.f, p4 * inv_n));
                const float cs = expf(consrc);
                css += cs;
                scomp[h] = cs / css * (float)(h+1);
            }
        }
        #pragma unroll
        for (int h = 0; h < 8; ++h) {
            f32x4 qs4, a4 = {0,0,0,0};
            #pragma unroll
            for (int j = 0; j < 4; ++j) qs4[j] = qh[h][j] * ir1[h];
            #pragma unroll
            for (int h2 = 0; h2 <= h; ++h2) {
                float p = 0.f;
                #pragma unroll
                for (int j = 0; j < 4; ++j) p += qs4[j] * kh[h2][j];
                p = red8(p);
                const float w = p * scomp[h2];
                #pragma unroll
                for (int j = 0; j < 4; ++j) a4[j] += w * vh[h2][j];
            }
            us4 o;
            #pragma unroll
            for (int j = 0; j < 4; ++j) o[j] = f2bf(a4[j] * salloc[h]);
            *reinterpret_cast<us4*>(abf + (size_t)bb*(H_*N_*D_) + (size_t)h*(N_*D_)
                                        + (size_t)nn*D_ + d0) = o;
        }
    }
}

// ---------------------------------------------------------------------------
// Kernel 2: out-projection + residual, 32 rows x 256 cols, wave owns 64 cols.
// Wo via the same wave-private DMA pipeline (4 steps). A rows are the
// SCRAMBLED flat slices of abf: out row gr=(n*B+b) <- abf[b*N*C + n*256 ..].
// ---------------------------------------------------------------------------
__global__ __launch_bounds__(256, 2)
void outproj(const unsigned short* __restrict__ abf,
             const unsigned short* __restrict__ wbf,
             const float* __restrict__ bo,
             const float* __restrict__ query,
             float* __restrict__ out)
{
    extern __shared__ char smem[];
    char* Wb = smem;                                     // 4 x (2 x 8 KB)
    unsigned char* As = (unsigned char*)(smem + 65536);  // 16 KB
    const int tid = threadIdx.x;
    const int r0  = blockIdx.x * BM2;
    const int wave = tid >> 6, lane = tid & 63;
    const int cw = wave * 64;
    char* mywb = Wb + wave * 16384;
    const unsigned short* Wo = wbf + 3*65536;

    stageW(Wo, 0, mywb, cw, lane);

    {   // stage scrambled A rows (pure bf16 copy)
        const int trow = tid >> 5, k0 = (tid & 31) * 8;
        #pragma unroll
        for (int i = 0; i < 4; ++i) {
            const int row = trow + i * 8;
            const int gr = r0 + row;
            const int nn = gr >> 3, bb = gr & 7;
            const short8 p = *reinterpret_cast<const short8*>(
                abf + (size_t)bb * (N_*C_) + (size_t)nn * C_ + k0);
            *reinterpret_cast<short8*>(As + swz(row, k0)) = p;
        }
    }

    const int lrow = lane & 15, kg8 = (lane >> 4) * 8;
    const int crow0 = (lane >> 4) * 4, ccol = lane & 15;

    // prefetch bias + residual
    float bov[4], qres[32];
    #pragma unroll
    for (int j = 0; j < 4; ++j) {
        const int ch = cw + j*16 + ccol;
        bov[j] = bo[ch];
        #pragma unroll
        for (int rh = 0; rh < 2; ++rh)
            #pragma unroll
            for (int r_ = 0; r_ < 4; ++r_)
                qres[j*8+rh*4+r_] =
                    query[(size_t)(r0 + rh*16 + crow0 + r_) * C_ + ch];
    }

    __syncthreads();

    f32x4 acc[2][4] = {};
    #pragma unroll
    for (int s = 0; s < 4; ++s) {
        if (s < 3) {
            stageW(Wo, (s+1)*64, mywb + ((s+1) & 1) * 8192, cw, lane);
            asm volatile("s_waitcnt vmcnt(8)" ::: "memory");
        } else {
            asm volatile("s_waitcnt vmcnt(0)" ::: "memory");
        }
        step_mm(As, mywb + (s & 1) * 8192, s*64, lrow, kg8, acc);
    }

    #pragma unroll
    for (int j = 0; j < 4; ++j) {
        const int ch = cw + j*16 + ccol;
        #pragma unroll
        for (int rh = 0; rh < 2; ++rh)
            #pragma unroll
            for (int r_ = 0; r_ < 4; ++r_) {
                const size_t g = (size_t)(r0 + rh*16 + crow0 + r_) * C_ + ch;
                out[g] = acc[rh][j][r_] + bov[j] + qres[j*8+rh*4+r_];
            }
    }
}

// ---------------------------------------------------------------------------
extern "C" void kernel_launch(void* const* d_in, const int* in_sizes, int n_in,
                              void* d_out, int out_size, void* d_ws, size_t ws_size,
                              hipStream_t stream)
{
    const float* query = (const float*)d_in[0];
    const float* key   = (const float*)d_in[1];
    const float* qpos  = (const float*)d_in[2];
    const float* kpos  = (const float*)d_in[3];
    const float* Wq = (const float*)d_in[4];  const float* bq = (const float*)d_in[5];
    const float* Wk = (const float*)d_in[6];  const float* bk = (const float*)d_in[7];
    const float* Wv = (const float*)d_in[8];  const float* bv = (const float*)d_in[9];
    const float* Wo = (const float*)d_in[10]; const float* bo = (const float*)d_in[11];

    unsigned short* wbf = (unsigned short*)d_ws;        // 4*65536 bf16 = 512 KB
    unsigned short* abf = wbf + 4*65536;                // B*N*C bf16 = 3.7 MB
    float* out = (float*)d_out;

    pack_w<<<128, 256, 0, stream>>>(Wq, Wk, Wv, Wo, wbf);
    fused_qkva<<<NBLK, 256, LDS1, stream>>>(query, key, qpos, kpos, wbf,
                                            bq, bk, bv, abf);
    outproj<<<NBLK, 256, LDS2, stream>>>(abf, wbf, bo, query, out);
}